// Round 7
// baseline (190.047 us; speedup 1.0000x reference)
//
#include <hip/hip_runtime.h>

typedef __bf16 bf16_t;
typedef __bf16 bf16x8 __attribute__((ext_vector_type(8)));
typedef float f32x4 __attribute__((ext_vector_type(4)));

#define BN 128
#define BK 64

// ws layout (bytes):
//   0        W1b   (512*512 bf16)  = 524288
//   524288   W2t   (512*512 bf16)  = 524288
//   1048576  W4t   (512*1536 bf16) = 1572864
//   2621440  Wct   (512*512 bf16)  = 524288
//   3145728  bc    (512 f32)       = 2048
//   3147776  u     (512 f32)       = 2048
//   3149824  Xb / A3 (overlapped; max = 24576*1536*2 = 75497472)

__device__ __forceinline__ void g2l16(const void* g, void* l) {
    __builtin_amdgcn_global_load_lds((__attribute__((address_space(1))) void*)(g),
                                     (__attribute__((address_space(3))) void*)(l),
                                     16, 0, 0);
}

#define SB()  __builtin_amdgcn_sched_barrier(0)
#define BAR() __builtin_amdgcn_s_barrier()

// 4-phase double-buffered 4-wave GEMM, tile (32*MF) x 128, BK=64.
// 256 threads, waves 2x2; per-wave tile (MF*16) x 64 -> MF2*2*2 MFMA/phase.
//   MF=6 -> BM=192: LDS = 2*(192+128)*64*2 = 80 KB -> 2 blocks/CU resident;
//           grid (512/128, 24576/192) = (4,128) = 512 blocks = 2/CU exact.
// Two independent blocks per CU overlap each other's barrier/drain stalls.
// Staging for tile t+1 is front-loaded (A in phase 1, B in phase 2) so the
// tile-boundary vmcnt(0) drains only >=2-phase-old (already landed) loads.
// LDS swizzle: byte ^= ((row&7)<<4), both-sides involution (inverse-swizzled
// global source + swizzled ds_read) -> 0 bank conflicts (verified R5).
template<int MF>
__global__ __launch_bounds__(256, 2)
void gemm_bt_kernel(const bf16_t* __restrict__ A, const bf16_t* __restrict__ Bt,
                    const float* __restrict__ bias, void* __restrict__ Cout,
                    int N, int K, int mode)
{
    constexpr int MF2    = MF / 2;
    constexpr int ABYTES = MF * 4096;          // per A buffer: MF*32 rows x 128B
    constexpr int RA     = MF;                 // A staging rounds (32 rows / 4KB each)

    __shared__ __align__(16) bf16_t lA[2][MF * 2048];
    __shared__ __align__(16) bf16_t lB[2][8192];     // 128 rows x 128B per buf

    const int tid  = threadIdx.x;
    const int lane = tid & 63;
    const int wave = tid >> 6;       // 0..3
    const int wr   = wave >> 1;      // 0..1
    const int wc   = wave & 1;       // 0..1
    const int l15  = lane & 15;
    const int lh   = lane >> 4;      // 0..3

    const int bn = blockIdx.x;
    const int bm = blockIdx.y;

    const size_t strb = (size_t)K * 2;

    // ---- staging: one g2l16 round = 4KB (32 rows x 128B), 256 thr x 16B ----
    const int q0 = tid * 16;                       // linear byte in round
    const size_t rowOff = (size_t)(q0 >> 7) * strb + ((q0 ^ (((q0 >> 7) & 7) << 4)) & 127);
    const char* gA = (const char*)A  + (size_t)bm * (MF * 32) * strb + rowOff;
    const char* gB = (const char*)Bt + (size_t)bn * BN * strb + rowOff;
    char* baseA = (char*)&lA[0][0];
    char* baseB = (char*)&lB[0][0];

    auto stageA = [&](int t, int buf, int r) {
        g2l16(gA + (size_t)t * 128 + (size_t)(r * 32) * strb,
              baseA + buf * ABYTES + r * 4096 + q0);
    };
    auto stageB = [&](int t, int buf, int r) {
        g2l16(gB + (size_t)t * 128 + (size_t)(r * 32) * strb,
              baseB + buf * 16384 + r * 4096 + q0);
    };

    // ---- swizzled read addresses ----
    const int swzr = (l15 & 7) << 4;
    const int xk0  = (lh * 16) ^ swzr;            // kk=0 column byte
    const int xk1  = (64 + lh * 16) ^ swzr;       // kk=1
    const int aOff = wr * (MF2 * 2) * 2048 + l15 * 128;
    const int bOff = wc * 8192 + l15 * 128;       // wc*64 rows

    f32x4 acc[2][2][MF2][2] = {};

#define LOADA(AF, BUF_, MH_) do{ \
    const char* _p = baseA + (BUF_)*ABYTES + aOff + (MH_)*(MF2*2048); \
    _Pragma("unroll") for (int m = 0; m < MF2; ++m) { \
        AF[m][0] = *(const bf16x8*)(_p + m*2048 + xk0); \
        AF[m][1] = *(const bf16x8*)(_p + m*2048 + xk1); } }while(0)
#define LOADB(BF, BUF_, NH_) do{ \
    const char* _p = baseB + (BUF_)*16384 + bOff + (NH_)*4096; \
    _Pragma("unroll") for (int n = 0; n < 2; ++n) { \
        BF[n][0] = *(const bf16x8*)(_p + n*2048 + xk0); \
        BF[n][1] = *(const bf16x8*)(_p + n*2048 + xk1); } }while(0)
#define MMAQ(MH_, NH_, AF, BF) do{ \
    __builtin_amdgcn_s_setprio(1); \
    _Pragma("unroll") for (int m = 0; m < MF2; ++m) \
    _Pragma("unroll") for (int n = 0; n < 2; ++n) \
    _Pragma("unroll") for (int kk = 0; kk < 2; ++kk) \
        acc[MH_][NH_][m][n] = __builtin_amdgcn_mfma_f32_16x16x32_bf16( \
            AF[m][kk], BF[n][kk], acc[MH_][NH_][m][n], 0, 0, 0); \
    __builtin_amdgcn_s_setprio(0); }while(0)

    const int T = K / BK;

    // prologue: stage tile 0 fully
#pragma unroll
    for (int r = 0; r < RA; ++r) stageA(0, 0, r);
#pragma unroll
    for (int r = 0; r < 4; ++r)  stageB(0, 0, r);
    asm volatile("s_waitcnt vmcnt(0)" ::: "memory");
    BAR();

    for (int t = 0; t < T; ++t) {
        const int buf = t & 1, nbuf = buf ^ 1;
        const bool pf = (t + 1 < T);
        bf16x8 a0[MF2][2], a1[MF2][2], b0[2][2], b1[2][2];

        // phase 1: quadrant (0,0); front-load ALL A stages for t+1
        LOADA(a0, buf, 0); LOADB(b0, buf, 0);
        if (pf) {
#pragma unroll
            for (int r = 0; r < RA; ++r) stageA(t + 1, nbuf, r);
        }
        SB(); BAR();
        MMAQ(0, 0, a0, b0);
        SB(); BAR();

        // phase 2: quadrant (0,1); all B stages for t+1
        LOADB(b1, buf, 1);
        if (pf) {
#pragma unroll
            for (int r = 0; r < 4; ++r) stageB(t + 1, nbuf, r);
        }
        SB(); BAR();
        MMAQ(0, 1, a0, b1);
        SB(); BAR();

        // phase 3: quadrant (1,0)
        LOADA(a1, buf, 1);
        SB(); BAR();
        MMAQ(1, 0, a1, b0);
        SB(); BAR();

        // phase 4: quadrant (1,1); boundary drain (loads are >=2 phases old)
        SB(); BAR();
        MMAQ(1, 1, a1, b1);
        SB();
        asm volatile("s_waitcnt vmcnt(0)" ::: "memory");
        BAR();
    }

    // C/D frag layout: col = lane&15, row = (lane>>4)*4 + j
    const int gr0 = bm * (MF * 32) + wr * (MF2 * 32) + lh * 4;
    const int gc0 = bn * BN + wc * 64 + l15;
    if (mode == 0) {
        bf16_t* C = (bf16_t*)Cout;
#pragma unroll
        for (int mh = 0; mh < 2; ++mh)
#pragma unroll
        for (int nh = 0; nh < 2; ++nh)
#pragma unroll
        for (int m = 0; m < MF2; ++m)
#pragma unroll
        for (int n = 0; n < 2; ++n) {
            const int c = gc0 + nh * 32 + n * 16;
            const float bv = bias ? bias[c] : 0.f;
#pragma unroll
            for (int j = 0; j < 4; ++j) {
                const int r = gr0 + (mh * MF2 + m) * 16 + j;
                C[(size_t)r * N + c] = (bf16_t)(acc[mh][nh][m][n][j] + bv);
            }
        }
    } else {
        float* C = (float*)Cout;
#pragma unroll
        for (int mh = 0; mh < 2; ++mh)
#pragma unroll
        for (int nh = 0; nh < 2; ++nh)
#pragma unroll
        for (int m = 0; m < MF2; ++m)
#pragma unroll
        for (int n = 0; n < 2; ++n) {
            const int c = gc0 + nh * 32 + n * 16;
            const float bv = bias[c];
#pragma unroll
            for (int j = 0; j < 4; ++j) {
                const int r = gr0 + (mh * MF2 + m) * 16 + j;
                float v = acc[mh][nh][m][n][j] + bv;
                C[(size_t)r * N + c] = v / (1.f + __expf(-v));
            }
        }
    }
#undef LOADA
#undef LOADB
#undef MMAQ
}

__global__ void cast8_kernel(const float* __restrict__ in, bf16_t* __restrict__ out, int n8) {
    const int i = blockIdx.x * blockDim.x + threadIdx.x;
    if (i >= n8) return;
    const float4* p = (const float4*)in + (size_t)i * 2;
    float4 a = p[0], b = p[1];
    bf16x8 v;
    v[0] = (bf16_t)a.x; v[1] = (bf16_t)a.y; v[2] = (bf16_t)a.z; v[3] = (bf16_t)a.w;
    v[4] = (bf16_t)b.x; v[5] = (bf16_t)b.y; v[6] = (bf16_t)b.z; v[7] = (bf16_t)b.w;
    *(bf16x8*)(out + (size_t)i * 8) = v;
}

// out[c*R + r] = in[r*C + c]   (in: R x C, out: C x R), cast to bf16
__global__ void transpose_cast_kernel(const float* __restrict__ in, bf16_t* __restrict__ out,
                                      int R, int C) {
    const int idx = blockIdx.x * blockDim.x + threadIdx.x;
    if (idx >= R * C) return;
    const int c = idx / R;
    const int r = idx - c * R;
    out[idx] = (bf16_t)in[(size_t)r * C + c];
}

// u[t] = sum_i v[i] * W[i][t]
__global__ void vecmat_kernel(const float* __restrict__ v, const float* __restrict__ W,
                              float* __restrict__ out) {
    const int t = blockIdx.x * blockDim.x + threadIdx.x;
    if (t >= 512) return;
    float s = 0.f;
    for (int i = 0; i < 512; ++i) s += v[i] * W[i * 512 + t];
    out[t] = s;
}

// per node: s = g.W3 ; chi_bo = chi*s ; A3[n, l*512+f] = c_l * g[f]^2
__global__ __launch_bounds__(256)
void mid_kernel(const bf16_t* __restrict__ G, const float* __restrict__ chi,
                const float* __restrict__ W3, float* __restrict__ chbo,
                bf16_t* __restrict__ A3)
{
    const int node = blockIdx.x * 4 + (threadIdx.x >> 6);
    const int lane = threadIdx.x & 63;

    const bf16x8 gv = *(const bf16x8*)(G + (size_t)node * 512 + lane * 8);
    float g[8];
#pragma unroll
    for (int j = 0; j < 8; ++j) g[j] = (float)gv[j];

    float s = 0.f;
    const float* w = W3 + lane * 8;
#pragma unroll
    for (int j = 0; j < 8; ++j) s += g[j] * w[j];
#pragma unroll
    for (int off = 32; off > 0; off >>= 1) s += __shfl_xor(s, off, 64);

    const float* ch = chi + (size_t)node * 15;
    float c0 = 0.f, c1 = 0.f, c2 = 0.f;
#pragma unroll
    for (int m = 0; m < 3; ++m)  c0 += ch[m] * ch[m];
#pragma unroll
    for (int m = 3; m < 8; ++m)  c1 += ch[m] * ch[m];
#pragma unroll
    for (int m = 8; m < 15; ++m) c2 += ch[m] * ch[m];

    if (lane < 15) chbo[(size_t)node * 15 + lane] = ch[lane] * s;

    const float cl[3] = {c0, c1, c2};
    bf16_t* arow = A3 + (size_t)node * 1536 + lane * 8;
#pragma unroll
    for (int l = 0; l < 3; ++l) {
        bf16x8 o;
#pragma unroll
        for (int j = 0; j < 8; ++j) o[j] = (bf16_t)(cl[l] * g[j] * g[j]);
        *(bf16x8*)(arow + l * 512) = o;
    }
}

extern "C" void kernel_launch(void* const* d_in, const int* in_sizes, int n_in,
                              void* d_out, int out_size, void* d_ws, size_t ws_size,
                              hipStream_t stream)
{
    const float* x   = (const float*)d_in[0];
    const float* chi = (const float*)d_in[1];
    // d_in[2] = z_one_hot : unused by the reference computation
    const float* W1  = (const float*)d_in[3];
    const float* b1  = (const float*)d_in[4];
    const float* W2  = (const float*)d_in[5];
    const float* W3  = (const float*)d_in[6];
    const float* W4  = (const float*)d_in[7];
    const float* b4  = (const float*)d_in[8];

    char* ws = (char*)d_ws;
    bf16_t* W1b = (bf16_t*)(ws + 0);
    bf16_t* W2t = (bf16_t*)(ws + 524288);
    bf16_t* W4t = (bf16_t*)(ws + 1048576);
    bf16_t* Wct = (bf16_t*)(ws + 2621440);
    float*  bc  = (float*) (ws + 3145728);
    float*  u   = (float*) (ws + 3147776);
    bf16_t* Xb  = (bf16_t*)(ws + 3149824);
    bf16_t* A3  = (bf16_t*)(ws + 3149824);   // overlaps Xb (dead by then)

    float*  xbo  = (float*)d_out;                                // 24576*512 f32
    float*  chbo = (float*)d_out + (size_t)24576 * 512;          // 24576*15 f32
    bf16_t* Gb   = (bf16_t*)d_out;   // bf16 scratch inside chunk0 (dead before final GEMM)

    // prep: casts / transposes / fused bias  bc = (b1 @ W1) @ W2
    cast8_kernel<<<6144, 256, 0, stream>>>(x, Xb, 1572864);
    cast8_kernel<<<128, 256, 0, stream>>>(W1, W1b, 32768);
    transpose_cast_kernel<<<1024, 256, 0, stream>>>(W2, W2t, 512, 512);
    transpose_cast_kernel<<<3072, 256, 0, stream>>>(W4, W4t, 1536, 512);
    vecmat_kernel<<<2, 256, 0, stream>>>(b1, W1, u);
    vecmat_kernel<<<2, 256, 0, stream>>>(u, W2, bc);

    // Wct = (W1@W2)^T = W2^T @ W1^T :  C[j][i] = sum_t W2t[j][t] * W1[i][t]
    gemm_bt_kernel<8><<<dim3(4, 2), 256, 0, stream>>>(W2t, W1b, nullptr, Wct, 512, 512, 0);

    // G = x @ (W1@W2) + bc : C[n][j] = sum_k Xb[n][k] * Wct[j][k] + bc[j]  -> bf16
    gemm_bt_kernel<6><<<dim3(4, 128), 256, 0, stream>>>(Xb, Wct, bc, Gb, 512, 512, 0);

    // s, chi_bo, A3
    mid_kernel<<<6144, 256, 0, stream>>>(Gb, chi, W3, chbo, A3);

    // x_bo = silu(A3 @ W4 + b4) : C[n][j] = sum_k A3[n][k] * W4t[j][k]
    gemm_bt_kernel<6><<<dim3(4, 128), 256, 0, stream>>>(A3, W4t, b4, xbo, 512, 1536, 1);
}